// Round 1
// baseline (905.850 us; speedup 1.0000x reference)
//
#include <hip/hip_runtime.h>

#define NNODES 50000
#define NEDGES 800000
#define INDIM  512
#define OUTD   512   // NUM_HEADS * OUT_DIM
#define NHEADS 8

typedef float  f32x4  __attribute__((ext_vector_type(4)));
typedef __bf16 bf16x8 __attribute__((ext_vector_type(8)));
typedef __bf16 bf16x4 __attribute__((ext_vector_type(4)));

__device__ __forceinline__ float lrelu(float x) { return x > 0.f ? x : 0.2f * x; }

// ---------------------------------------------------------------------------
// GEMM: h = leaky_relu(feat @ W^T + b)  [50000 x 512], bf16 MFMA, f32 acc.
// Epilogue also computes e_src/e_dst = sum_d h*w_att (from f32 accumulators).
// Tile 128x128, BK=32, 4 waves (2x2), each wave 64x64 = 4x4 16x16 fragments.
// ---------------------------------------------------------------------------
constexpr int BM = 128, BN = 128, BK = 32, LDA = BK + 8;  // +8 bf16 = 16B pad

__global__ __launch_bounds__(256) void gemm_h(
    const float* __restrict__ feat, const float* __restrict__ W,
    const float* __restrict__ bias, const float* __restrict__ w_s,
    const float* __restrict__ w_d, __bf16* __restrict__ hout,
    float* __restrict__ esrc, float* __restrict__ edst)
{
    __shared__ __bf16 As[BM][LDA];
    __shared__ __bf16 Bs[BN][LDA];
    const int row0 = blockIdx.x * BM;
    const int col0 = blockIdx.y * BN;
    const int tid  = threadIdx.x;
    const int lane = tid & 63;
    const int w    = tid >> 6;
    const int wr   = w >> 1, wc = w & 1;
    const int lr   = lane & 15, kg = lane >> 4;

    f32x4 acc[4][4] = {};

    for (int k0 = 0; k0 < INDIM; k0 += BK) {
        #pragma unroll
        for (int i = 0; i < 4; ++i) {
            int idx = tid + 256 * i;          // 0..1023
            int r = idx >> 3, c4 = idx & 7;   // 128 rows x 8 float4
            int gr = row0 + r;
            f32x4 v = {0.f, 0.f, 0.f, 0.f};
            if (gr < NNODES) v = *(const f32x4*)(feat + (size_t)gr * INDIM + k0 + c4 * 4);
            bf16x4 bv; bv[0]=(__bf16)v[0]; bv[1]=(__bf16)v[1]; bv[2]=(__bf16)v[2]; bv[3]=(__bf16)v[3];
            *(bf16x4*)&As[r][c4 * 4] = bv;
            f32x4 u = *(const f32x4*)(W + (size_t)(col0 + r) * INDIM + k0 + c4 * 4);
            bf16x4 bu; bu[0]=(__bf16)u[0]; bu[1]=(__bf16)u[1]; bu[2]=(__bf16)u[2]; bu[3]=(__bf16)u[3];
            *(bf16x4*)&Bs[r][c4 * 4] = bu;
        }
        __syncthreads();
        bf16x8 af[4], bf[4];
        #pragma unroll
        for (int mi = 0; mi < 4; ++mi) af[mi] = *(const bf16x8*)&As[wr * 64 + mi * 16 + lr][kg * 8];
        #pragma unroll
        for (int ni = 0; ni < 4; ++ni) bf[ni] = *(const bf16x8*)&Bs[wc * 64 + ni * 16 + lr][kg * 8];
        #pragma unroll
        for (int mi = 0; mi < 4; ++mi)
            #pragma unroll
            for (int ni = 0; ni < 4; ++ni)
                acc[mi][ni] = __builtin_amdgcn_mfma_f32_16x16x32_bf16(af[mi], bf[ni], acc[mi][ni], 0, 0, 0);
        __syncthreads();
    }

    // epilogue: bias + leakyrelu, store bf16 h, fused per-head logits
    float cb[4], wsv[4], wdv[4];
    #pragma unroll
    for (int ni = 0; ni < 4; ++ni) {
        int c = col0 + wc * 64 + ni * 16 + lr;
        cb[ni]  = bias[c];
        wsv[ni] = w_s[c];   // flat [H*D]: head*64+d == c
        wdv[ni] = w_d[c];
    }
    const int head = (col0 + wc * 64) >> 6;   // wave spans exactly one head
    #pragma unroll
    for (int mi = 0; mi < 4; ++mi) {
        #pragma unroll
        for (int reg = 0; reg < 4; ++reg) {
            int r = row0 + wr * 64 + mi * 16 + kg * 4 + reg;   // C/D: row=(l>>4)*4+reg
            bool valid = r < NNODES;
            float vs = 0.f, vd = 0.f;
            #pragma unroll
            for (int ni = 0; ni < 4; ++ni) {
                int c = col0 + wc * 64 + ni * 16 + lr;          // C/D: col=l&15
                float v = acc[mi][ni][reg] + cb[ni];
                v = lrelu(v);
                if (valid) hout[(size_t)r * OUTD + c] = (__bf16)v;
                vs += v * wsv[ni];
                vd += v * wdv[ni];
            }
            #pragma unroll
            for (int m = 1; m < 16; m <<= 1) { vs += __shfl_xor(vs, m); vd += __shfl_xor(vd, m); }
            if (valid && lr == 0) {   // sole owner of (r, head): plain store
                esrc[r * NHEADS + head] = vs;
                edst[r * NHEADS + head] = vd;
            }
        }
    }
}

// ---------------------------------------------------------------------------
// CSR build: histogram -> 3-phase scan -> scatter
// ---------------------------------------------------------------------------
__global__ void hist_k(const int* __restrict__ dstv, int* __restrict__ deg)
{
    int e = blockIdx.x * blockDim.x + threadIdx.x;
    if (e < NEDGES) atomicAdd(&deg[dstv[e]], 1);
}

__global__ __launch_bounds__(256) void scan_bsums(const int* __restrict__ deg, int* __restrict__ bsums)
{
    __shared__ int sd[256];
    int t = threadIdx.x, base = blockIdx.x * 1024, sum = 0;
    #pragma unroll
    for (int i = 0; i < 4; ++i) { int idx = base + t * 4 + i; if (idx < NNODES) sum += deg[idx]; }
    sd[t] = sum; __syncthreads();
    for (int st = 128; st > 0; st >>= 1) { if (t < st) sd[t] += sd[t + st]; __syncthreads(); }
    if (t == 0) bsums[blockIdx.x] = sd[0];
}

__global__ void scan_partials(int* __restrict__ bsums)   // 49 partials, one wave
{
    int l = threadIdx.x;
    int orig = (l < 49) ? bsums[l] : 0;
    int v = orig;
    #pragma unroll
    for (int d = 1; d < 64; d <<= 1) { int u = __shfl_up(v, d); if (l >= d) v += u; }
    if (l < 49) bsums[l] = v - orig;   // exclusive
}

__global__ __launch_bounds__(256) void scan_final(
    const int* __restrict__ deg, const int* __restrict__ bsums, int* __restrict__ offs)
{
    __shared__ int sd[256];
    int t = threadIdx.x, base = blockIdx.x * 1024;
    int v[4]; int sum = 0;
    #pragma unroll
    for (int i = 0; i < 4; ++i) { int idx = base + t * 4 + i; v[i] = (idx < NNODES) ? deg[idx] : 0; sum += v[i]; }
    sd[t] = sum; __syncthreads();
    int val = sum;
    for (int st = 1; st < 256; st <<= 1) {
        int add = (t >= st) ? sd[t - st] : 0;
        __syncthreads();
        val += add; sd[t] = val;
        __syncthreads();
    }
    int run = bsums[blockIdx.x] + (val - sum);
    #pragma unroll
    for (int i = 0; i < 4; ++i) { int idx = base + t * 4 + i; if (idx < NNODES) offs[idx] = run; run += v[i]; }
    if (blockIdx.x == 0 && t == 0) offs[NNODES] = NEDGES;
}

__global__ void scatter_k(const int* __restrict__ dstv, int* __restrict__ cursor, int* __restrict__ eidx)
{
    int e = blockIdx.x * blockDim.x + threadIdx.x;
    if (e < NEDGES) { int pos = atomicAdd(&cursor[dstv[e]], 1); eidx[pos] = e; }
}

// ---------------------------------------------------------------------------
// Edge pass: p = exp(leaky(e_src[src]+e_dst[dst])) (max-free, no overflow);
// denominators via atomicAdd into s[N,8] (L2-resident).
// ---------------------------------------------------------------------------
__global__ void edge_p(const int* __restrict__ src, const int* __restrict__ dstv,
                       const float* __restrict__ esrc, const float* __restrict__ edst,
                       float* __restrict__ p, float* __restrict__ s)
{
    int e = blockIdx.x * blockDim.x + threadIdx.x;
    if (e >= NEDGES) return;
    int a = src[e], b = dstv[e];
    f32x4 s0 = *(const f32x4*)(esrc + (size_t)a * 8);
    f32x4 s1 = *(const f32x4*)(esrc + (size_t)a * 8 + 4);
    f32x4 d0 = *(const f32x4*)(edst + (size_t)b * 8);
    f32x4 d1 = *(const f32x4*)(edst + (size_t)b * 8 + 4);
    f32x4 p0, p1;
    #pragma unroll
    for (int j = 0; j < 4; ++j) {
        p0[j] = __expf(lrelu(s0[j] + d0[j]));
        p1[j] = __expf(lrelu(s1[j] + d1[j]));
    }
    *(f32x4*)(p + (size_t)e * 8)     = p0;
    *(f32x4*)(p + (size_t)e * 8 + 4) = p1;
    #pragma unroll
    for (int j = 0; j < 4; ++j) {
        atomicAdd(&s[(size_t)b * 8 + j],     p0[j]);
        atomicAdd(&s[(size_t)b * 8 + 4 + j], p1[j]);
    }
}

// ---------------------------------------------------------------------------
// Aggregation: one wave per dst node; lane l owns output cols [8l, 8l+8).
// out[n,:] = sum_e (p/s * dist) * h[src[e],:]
// ---------------------------------------------------------------------------
__global__ __launch_bounds__(256) void agg_k(
    const int* __restrict__ offs, const int* __restrict__ eidx,
    const int* __restrict__ src, const float* __restrict__ p,
    const float* __restrict__ s, const float* __restrict__ dist,
    const __bf16* __restrict__ hmat, float* __restrict__ out)
{
    int node = blockIdx.x * 4 + (threadIdx.x >> 6);
    int lane = threadIdx.x & 63;
    if (node >= NNODES) return;
    const int head = lane >> 3;
    float sv = s[(size_t)node * 8 + head];
    float sinv = sv > 0.f ? 1.f / sv : 0.f;
    int beg = offs[node], end = offs[node + 1];
    float acc[8] = {0.f, 0.f, 0.f, 0.f, 0.f, 0.f, 0.f, 0.f};
    for (int pos = beg; pos < end; ++pos) {
        int e  = eidx[pos];
        int sn = src[e];
        float a = p[(size_t)e * 8 + head] * dist[(size_t)e * 8 + head] * sinv;
        bf16x8 hv = *(const bf16x8*)(hmat + (size_t)sn * OUTD + lane * 8);
        #pragma unroll
        for (int j = 0; j < 8; ++j) acc[j] += a * (float)hv[j];
    }
    f32x4 o0 = {acc[0], acc[1], acc[2], acc[3]};
    f32x4 o1 = {acc[4], acc[5], acc[6], acc[7]};
    *(f32x4*)(out + (size_t)node * OUTD + lane * 8)     = o0;
    *(f32x4*)(out + (size_t)node * OUTD + lane * 8 + 4) = o1;
}

// ---------------------------------------------------------------------------
extern "C" void kernel_launch(void* const* d_in, const int* in_sizes, int n_in,
                              void* d_out, int out_size, void* d_ws, size_t ws_size,
                              hipStream_t stream)
{
    const float* feat = (const float*)d_in[0];
    const float* dist = (const float*)d_in[1];
    const int*   src  = (const int*)d_in[2];
    const int*   dstv = (const int*)d_in[3];
    const float* W    = (const float*)d_in[4];
    const float* bias = (const float*)d_in[5];
    const float* w_s  = (const float*)d_in[6];
    const float* w_d  = (const float*)d_in[7];
    float* out = (float*)d_out;

    char* wsb = (char*)d_ws;
    size_t off = 0;
    auto alloc = [&](size_t bytes) -> char* {
        char* r = wsb + off;
        off = (off + bytes + 255) & ~(size_t)255;
        return r;
    };
    __bf16* hmat  = (__bf16*)alloc((size_t)NNODES * OUTD * 2);   // 51.2 MB
    float*  esrc  = (float*)alloc((size_t)NNODES * NHEADS * 4);  // 1.6 MB
    float*  edst  = (float*)alloc((size_t)NNODES * NHEADS * 4);
    float*  p     = (float*)alloc((size_t)NEDGES * NHEADS * 4);  // 25.6 MB
    float*  s     = (float*)alloc((size_t)NNODES * NHEADS * 4);
    int*    deg   = (int*)alloc((size_t)NNODES * 4);
    int*    offs  = (int*)alloc((size_t)(NNODES + 1) * 4);
    int*    cursor= (int*)alloc((size_t)NNODES * 4);
    int*    eidx  = (int*)alloc((size_t)NEDGES * 4);             // 3.2 MB
    int*    bsums = (int*)alloc(64 * 4);

    hipMemsetAsync(deg, 0, (size_t)NNODES * 4, stream);
    hipMemsetAsync(s,   0, (size_t)NNODES * NHEADS * 4, stream);

    gemm_h<<<dim3((NNODES + BM - 1) / BM, OUTD / BN), 256, 0, stream>>>(
        feat, W, bias, w_s, w_d, hmat, esrc, edst);

    hist_k<<<(NEDGES + 255) / 256, 256, 0, stream>>>(dstv, deg);
    scan_bsums<<<49, 256, 0, stream>>>(deg, bsums);
    scan_partials<<<1, 64, 0, stream>>>(bsums);
    scan_final<<<49, 256, 0, stream>>>(deg, bsums, offs);
    hipMemcpyAsync(cursor, offs, (size_t)NNODES * 4, hipMemcpyDeviceToDevice, stream);
    scatter_k<<<(NEDGES + 255) / 256, 256, 0, stream>>>(dstv, cursor, eidx);

    edge_p<<<(NEDGES + 255) / 256, 256, 0, stream>>>(src, dstv, esrc, edst, p, s);

    agg_k<<<(NNODES + 3) / 4, 256, 0, stream>>>(offs, eidx, src, p, s, dist, hmat, out);
}

// Round 4
// 554.551 us; speedup vs baseline: 1.6335x; 1.6335x over previous
//
#include <hip/hip_runtime.h>

#define NNODES 50000
#define NEDGES 800000
#define INDIM  512
#define OUTD   512   // NUM_HEADS * OUT_DIM
#define NHEADS 8

typedef float  f32x4  __attribute__((ext_vector_type(4)));
typedef __bf16 bf16x8 __attribute__((ext_vector_type(8)));
typedef __bf16 bf16x4 __attribute__((ext_vector_type(4)));

__device__ __forceinline__ float lrelu(float x) { return x > 0.f ? x : 0.2f * x; }

// ---------------------------------------------------------------------------
// GEMM: h = leaky_relu(feat @ W^T + b)  [50000 x 512], bf16 MFMA, f32 acc.
// Epilogue also computes e_src/e_dst = sum_d h*w_att (from f32 accumulators).
// Tile 128x128, BK=32, 4 waves (2x2), each wave 64x64 = 4x4 16x16 fragments.
// ---------------------------------------------------------------------------
constexpr int BM = 128, BN = 128, BK = 32, LDA = BK + 8;  // +8 bf16 = 16B pad

__global__ __launch_bounds__(256) void gemm_h(
    const float* __restrict__ feat, const float* __restrict__ W,
    const float* __restrict__ bias, const float* __restrict__ w_s,
    const float* __restrict__ w_d, __bf16* __restrict__ hout,
    float* __restrict__ esrc, float* __restrict__ edst)
{
    __shared__ __bf16 As[BM][LDA];
    __shared__ __bf16 Bs[BN][LDA];
    const int row0 = blockIdx.x * BM;
    const int col0 = blockIdx.y * BN;
    const int tid  = threadIdx.x;
    const int lane = tid & 63;
    const int w    = tid >> 6;
    const int wr   = w >> 1, wc = w & 1;
    const int lr   = lane & 15, kg = lane >> 4;

    f32x4 acc[4][4] = {};

    for (int k0 = 0; k0 < INDIM; k0 += BK) {
        #pragma unroll
        for (int i = 0; i < 4; ++i) {
            int idx = tid + 256 * i;          // 0..1023
            int r = idx >> 3, c4 = idx & 7;   // 128 rows x 8 float4
            int gr = row0 + r;
            f32x4 v = {0.f, 0.f, 0.f, 0.f};
            if (gr < NNODES) v = *(const f32x4*)(feat + (size_t)gr * INDIM + k0 + c4 * 4);
            bf16x4 bv; bv[0]=(__bf16)v[0]; bv[1]=(__bf16)v[1]; bv[2]=(__bf16)v[2]; bv[3]=(__bf16)v[3];
            *(bf16x4*)&As[r][c4 * 4] = bv;
            f32x4 u = *(const f32x4*)(W + (size_t)(col0 + r) * INDIM + k0 + c4 * 4);
            bf16x4 bu; bu[0]=(__bf16)u[0]; bu[1]=(__bf16)u[1]; bu[2]=(__bf16)u[2]; bu[3]=(__bf16)u[3];
            *(bf16x4*)&Bs[r][c4 * 4] = bu;
        }
        __syncthreads();
        bf16x8 af[4], bf[4];
        #pragma unroll
        for (int mi = 0; mi < 4; ++mi) af[mi] = *(const bf16x8*)&As[wr * 64 + mi * 16 + lr][kg * 8];
        #pragma unroll
        for (int ni = 0; ni < 4; ++ni) bf[ni] = *(const bf16x8*)&Bs[wc * 64 + ni * 16 + lr][kg * 8];
        #pragma unroll
        for (int mi = 0; mi < 4; ++mi)
            #pragma unroll
            for (int ni = 0; ni < 4; ++ni)
                acc[mi][ni] = __builtin_amdgcn_mfma_f32_16x16x32_bf16(af[mi], bf[ni], acc[mi][ni], 0, 0, 0);
        __syncthreads();
    }

    // epilogue: bias + leakyrelu, store bf16 h, fused per-head logits
    float cb[4], wsv[4], wdv[4];
    #pragma unroll
    for (int ni = 0; ni < 4; ++ni) {
        int c = col0 + wc * 64 + ni * 16 + lr;
        cb[ni]  = bias[c];
        wsv[ni] = w_s[c];   // flat [H*D]: head*64+d == c
        wdv[ni] = w_d[c];
    }
    const int head = (col0 + wc * 64) >> 6;   // wave spans exactly one head
    #pragma unroll
    for (int mi = 0; mi < 4; ++mi) {
        #pragma unroll
        for (int reg = 0; reg < 4; ++reg) {
            int r = row0 + wr * 64 + mi * 16 + kg * 4 + reg;   // C/D: row=(l>>4)*4+reg
            bool valid = r < NNODES;
            float vs = 0.f, vd = 0.f;
            #pragma unroll
            for (int ni = 0; ni < 4; ++ni) {
                int c = col0 + wc * 64 + ni * 16 + lr;          // C/D: col=l&15
                float v = acc[mi][ni][reg] + cb[ni];
                v = lrelu(v);
                if (valid) hout[(size_t)r * OUTD + c] = (__bf16)v;
                vs += v * wsv[ni];
                vd += v * wdv[ni];
            }
            #pragma unroll
            for (int m = 1; m < 16; m <<= 1) { vs += __shfl_xor(vs, m); vd += __shfl_xor(vd, m); }
            if (valid && lr == 0) {   // sole owner of (r, head): plain store
                esrc[r * NHEADS + head] = vs;
                edst[r * NHEADS + head] = vd;
            }
        }
    }
}

// ---------------------------------------------------------------------------
// CSR build: histogram -> 3-phase scan -> scatter
// ---------------------------------------------------------------------------
__global__ void hist_k(const int* __restrict__ dstv, int* __restrict__ deg)
{
    int e = blockIdx.x * blockDim.x + threadIdx.x;
    if (e < NEDGES) atomicAdd(&deg[dstv[e]], 1);
}

__global__ __launch_bounds__(256) void scan_bsums(const int* __restrict__ deg, int* __restrict__ bsums)
{
    __shared__ int sd[256];
    int t = threadIdx.x, base = blockIdx.x * 1024, sum = 0;
    #pragma unroll
    for (int i = 0; i < 4; ++i) { int idx = base + t * 4 + i; if (idx < NNODES) sum += deg[idx]; }
    sd[t] = sum; __syncthreads();
    for (int st = 128; st > 0; st >>= 1) { if (t < st) sd[t] += sd[t + st]; __syncthreads(); }
    if (t == 0) bsums[blockIdx.x] = sd[0];
}

__global__ void scan_partials(int* __restrict__ bsums)   // 49 partials, one wave
{
    int l = threadIdx.x;
    int orig = (l < 49) ? bsums[l] : 0;
    int v = orig;
    #pragma unroll
    for (int d = 1; d < 64; d <<= 1) { int u = __shfl_up(v, d); if (l >= d) v += u; }
    if (l < 49) bsums[l] = v - orig;   // exclusive
}

__global__ __launch_bounds__(256) void scan_final(
    const int* __restrict__ deg, const int* __restrict__ bsums, int* __restrict__ offs)
{
    __shared__ int sd[256];
    int t = threadIdx.x, base = blockIdx.x * 1024;
    int v[4]; int sum = 0;
    #pragma unroll
    for (int i = 0; i < 4; ++i) { int idx = base + t * 4 + i; v[i] = (idx < NNODES) ? deg[idx] : 0; sum += v[i]; }
    sd[t] = sum; __syncthreads();
    int val = sum;
    for (int st = 1; st < 256; st <<= 1) {
        int add = (t >= st) ? sd[t - st] : 0;
        __syncthreads();
        val += add; sd[t] = val;
        __syncthreads();
    }
    int run = bsums[blockIdx.x] + (val - sum);
    #pragma unroll
    for (int i = 0; i < 4; ++i) { int idx = base + t * 4 + i; if (idx < NNODES) offs[idx] = run; run += v[i]; }
    if (blockIdx.x == 0 && t == 0) offs[NNODES] = NEDGES;
}

__global__ void scatter_k(const int* __restrict__ dstv, int* __restrict__ cursor, int* __restrict__ eidx)
{
    int e = blockIdx.x * blockDim.x + threadIdx.x;
    if (e < NEDGES) { int pos = atomicAdd(&cursor[dstv[e]], 1); eidx[pos] = e; }
}

// ---------------------------------------------------------------------------
// Aggregation (fused softmax): one wave per dst node; lane l owns cols
// [8l, 8l+8), head = l>>3.
//   ex_e   = exp(lrelu(esrc[src[e],h] + edst[node,h]))   (max-free: logits
//            ~N(0,64), |e| << 88, so exp can't overflow and normalization
//            is mathematically identical to the max-subtracted form)
//   out    = (sum_e ex*dist*h[src]) / (sum_e ex)
// No atomics anywhere; denominator reduced in-register per wave.
// ---------------------------------------------------------------------------
__global__ __launch_bounds__(256) void agg_k(
    const int* __restrict__ offs, const int* __restrict__ eidx,
    const int* __restrict__ src, const float* __restrict__ esrc,
    const float* __restrict__ edst, const float* __restrict__ dist,
    const __bf16* __restrict__ hmat, float* __restrict__ out)
{
    int node = blockIdx.x * 4 + (threadIdx.x >> 6);
    int lane = threadIdx.x & 63;
    if (node >= NNODES) return;
    const int head = lane >> 3;
    const float edv = edst[(size_t)node * NHEADS + head];
    int beg = offs[node], end = offs[node + 1];
    float denom = 0.f;
    float acc[8] = {0.f, 0.f, 0.f, 0.f, 0.f, 0.f, 0.f, 0.f};

    if (beg < end) {
        // prefetch edge 0
        int e  = eidx[beg];
        int sn = src[e];
        for (int pos = beg; pos < end; ++pos) {
            int e_cur = e, sn_cur = sn;
            if (pos + 1 < end) {           // prefetch next: break dep chain
                e  = eidx[pos + 1];
                sn = src[e];
            }
            float ex = __expf(lrelu(esrc[(size_t)sn_cur * NHEADS + head] + edv));
            float a  = ex * dist[(size_t)e_cur * NHEADS + head];
            denom += ex;
            bf16x8 hv = *(const bf16x8*)(hmat + (size_t)sn_cur * OUTD + lane * 8);
            #pragma unroll
            for (int j = 0; j < 8; ++j) acc[j] += a * (float)hv[j];
        }
    }

    float sinv = denom > 0.f ? 1.f / denom : 0.f;
    f32x4 o0 = {acc[0] * sinv, acc[1] * sinv, acc[2] * sinv, acc[3] * sinv};
    f32x4 o1 = {acc[4] * sinv, acc[5] * sinv, acc[6] * sinv, acc[7] * sinv};
    *(f32x4*)(out + (size_t)node * OUTD + lane * 8)     = o0;
    *(f32x4*)(out + (size_t)node * OUTD + lane * 8 + 4) = o1;
}

// ---------------------------------------------------------------------------
extern "C" void kernel_launch(void* const* d_in, const int* in_sizes, int n_in,
                              void* d_out, int out_size, void* d_ws, size_t ws_size,
                              hipStream_t stream)
{
    const float* feat = (const float*)d_in[0];
    const float* dist = (const float*)d_in[1];
    const int*   src  = (const int*)d_in[2];
    const int*   dstv = (const int*)d_in[3];
    const float* W    = (const float*)d_in[4];
    const float* bias = (const float*)d_in[5];
    const float* w_s  = (const float*)d_in[6];
    const float* w_d  = (const float*)d_in[7];
    float* out = (float*)d_out;

    char* wsb = (char*)d_ws;
    size_t off = 0;
    auto alloc = [&](size_t bytes) -> char* {
        char* r = wsb + off;
        off = (off + bytes + 255) & ~(size_t)255;
        return r;
    };
    __bf16* hmat  = (__bf16*)alloc((size_t)NNODES * OUTD * 2);   // 51.2 MB
    float*  esrc  = (float*)alloc((size_t)NNODES * NHEADS * 4);  // 1.6 MB
    float*  edst  = (float*)alloc((size_t)NNODES * NHEADS * 4);
    int*    deg   = (int*)alloc((size_t)NNODES * 4);
    int*    offs  = (int*)alloc((size_t)(NNODES + 1) * 4);
    int*    cursor= (int*)alloc((size_t)NNODES * 4);
    int*    eidx  = (int*)alloc((size_t)NEDGES * 4);             // 3.2 MB
    int*    bsums = (int*)alloc(64 * 4);

    hipMemsetAsync(deg, 0, (size_t)NNODES * 4, stream);

    gemm_h<<<dim3((NNODES + BM - 1) / BM, OUTD / BN), 256, 0, stream>>>(
        feat, W, bias, w_s, w_d, hmat, esrc, edst);

    hist_k<<<(NEDGES + 255) / 256, 256, 0, stream>>>(dstv, deg);
    scan_bsums<<<49, 256, 0, stream>>>(deg, bsums);
    scan_partials<<<1, 64, 0, stream>>>(bsums);
    scan_final<<<49, 256, 0, stream>>>(deg, bsums, offs);
    hipMemcpyAsync(cursor, offs, (size_t)NNODES * 4, hipMemcpyDeviceToDevice, stream);
    scatter_k<<<(NEDGES + 255) / 256, 256, 0, stream>>>(dstv, cursor, eidx);

    agg_k<<<(NNODES + 3) / 4, 256, 0, stream>>>(offs, eidx, src, esrc, edst, dist, hmat, out);
}

// Round 6
// 524.342 us; speedup vs baseline: 1.7276x; 1.0576x over previous
//
#include <hip/hip_runtime.h>

#define NNODES 50000
#define NEDGES 800000
#define INDIM  512
#define OUTD   512   // NUM_HEADS * OUT_DIM
#define NHEADS 8

typedef float  f32x4  __attribute__((ext_vector_type(4)));
typedef __bf16 bf16x8 __attribute__((ext_vector_type(8)));
typedef __bf16 bf16x4 __attribute__((ext_vector_type(4)));

__device__ __forceinline__ float lrelu(float x) { return x > 0.f ? x : 0.2f * x; }

// ---------------------------------------------------------------------------
// GEMM: h = leaky_relu(feat @ W^T + b)  [50000 x 512], bf16 MFMA, f32 acc.
// Epilogue computes e_src/e_dst from the f32 accumulators. Also fused: the
// per-dst edge histogram (independent atomic work hidden under MFMA compute).
// ---------------------------------------------------------------------------
constexpr int BM = 128, BN = 128, BK = 32, LDA = BK + 8;  // +8 bf16 = 16B pad

__global__ __launch_bounds__(256) void gemm_h(
    const float* __restrict__ feat, const float* __restrict__ W,
    const float* __restrict__ bias, const float* __restrict__ w_s,
    const float* __restrict__ w_d, __bf16* __restrict__ hout,
    float* __restrict__ esrc, float* __restrict__ edst,
    const int* __restrict__ dstv, int* __restrict__ deg)
{
    __shared__ __bf16 As[BM][LDA];
    __shared__ __bf16 Bs[BN][LDA];
    const int row0 = blockIdx.x * BM;
    const int col0 = blockIdx.y * BN;
    const int tid  = threadIdx.x;

    // ---- fused edge histogram: this block's 512-edge slice ----
    {
        int bid = blockIdx.y * gridDim.x + blockIdx.x;   // 0..1563
        int lo = bid * 512, hi = lo + 512;
        if (hi > NEDGES) hi = NEDGES;
        for (int e = lo + tid; e < hi; e += 256)
            atomicAdd(&deg[dstv[e]], 1);
    }

    const int lane = tid & 63;
    const int w    = tid >> 6;
    const int wr   = w >> 1, wc = w & 1;
    const int lr   = lane & 15, kg = lane >> 4;

    f32x4 acc[4][4] = {};

    for (int k0 = 0; k0 < INDIM; k0 += BK) {
        #pragma unroll
        for (int i = 0; i < 4; ++i) {
            int idx = tid + 256 * i;          // 0..1023
            int r = idx >> 3, c4 = idx & 7;   // 128 rows x 8 float4
            int gr = row0 + r;
            f32x4 v = {0.f, 0.f, 0.f, 0.f};
            if (gr < NNODES) v = *(const f32x4*)(feat + (size_t)gr * INDIM + k0 + c4 * 4);
            bf16x4 bv; bv[0]=(__bf16)v[0]; bv[1]=(__bf16)v[1]; bv[2]=(__bf16)v[2]; bv[3]=(__bf16)v[3];
            *(bf16x4*)&As[r][c4 * 4] = bv;
            f32x4 u = *(const f32x4*)(W + (size_t)(col0 + r) * INDIM + k0 + c4 * 4);
            bf16x4 bu; bu[0]=(__bf16)u[0]; bu[1]=(__bf16)u[1]; bu[2]=(__bf16)u[2]; bu[3]=(__bf16)u[3];
            *(bf16x4*)&Bs[r][c4 * 4] = bu;
        }
        __syncthreads();
        bf16x8 af[4], bf[4];
        #pragma unroll
        for (int mi = 0; mi < 4; ++mi) af[mi] = *(const bf16x8*)&As[wr * 64 + mi * 16 + lr][kg * 8];
        #pragma unroll
        for (int ni = 0; ni < 4; ++ni) bf[ni] = *(const bf16x8*)&Bs[wc * 64 + ni * 16 + lr][kg * 8];
        #pragma unroll
        for (int mi = 0; mi < 4; ++mi)
            #pragma unroll
            for (int ni = 0; ni < 4; ++ni)
                acc[mi][ni] = __builtin_amdgcn_mfma_f32_16x16x32_bf16(af[mi], bf[ni], acc[mi][ni], 0, 0, 0);
        __syncthreads();
    }

    // epilogue: bias + leakyrelu, store bf16 h, fused per-head logits
    float cb[4], wsv[4], wdv[4];
    #pragma unroll
    for (int ni = 0; ni < 4; ++ni) {
        int c = col0 + wc * 64 + ni * 16 + lr;
        cb[ni]  = bias[c];
        wsv[ni] = w_s[c];   // flat [H*D]: head*64+d == c
        wdv[ni] = w_d[c];
    }
    const int head = (col0 + wc * 64) >> 6;   // wave spans exactly one head
    #pragma unroll
    for (int mi = 0; mi < 4; ++mi) {
        #pragma unroll
        for (int reg = 0; reg < 4; ++reg) {
            int r = row0 + wr * 64 + mi * 16 + kg * 4 + reg;   // C/D: row=(l>>4)*4+reg
            bool valid = r < NNODES;
            float vs = 0.f, vd = 0.f;
            #pragma unroll
            for (int ni = 0; ni < 4; ++ni) {
                int c = col0 + wc * 64 + ni * 16 + lr;          // C/D: col=l&15
                float v = acc[mi][ni][reg] + cb[ni];
                v = lrelu(v);
                if (valid) hout[(size_t)r * OUTD + c] = (__bf16)v;
                vs += v * wsv[ni];
                vd += v * wdv[ni];
            }
            #pragma unroll
            for (int m = 1; m < 16; m <<= 1) { vs += __shfl_xor(vs, m); vd += __shfl_xor(vd, m); }
            if (valid && lr == 0) {   // sole owner of (r, head): plain store
                esrc[r * NHEADS + head] = vs;
                edst[r * NHEADS + head] = vd;
            }
        }
    }
}

// ---------------------------------------------------------------------------
// CSR build: (histogram fused into gemm_h) -> 3-phase scan -> scatter
// ---------------------------------------------------------------------------
__global__ __launch_bounds__(256) void scan_bsums(const int* __restrict__ deg, int* __restrict__ bsums)
{
    __shared__ int sd[256];
    int t = threadIdx.x, base = blockIdx.x * 1024, sum = 0;
    #pragma unroll
    for (int i = 0; i < 4; ++i) { int idx = base + t * 4 + i; if (idx < NNODES) sum += deg[idx]; }
    sd[t] = sum; __syncthreads();
    for (int st = 128; st > 0; st >>= 1) { if (t < st) sd[t] += sd[t + st]; __syncthreads(); }
    if (t == 0) bsums[blockIdx.x] = sd[0];
}

__global__ void scan_partials(int* __restrict__ bsums)   // 49 partials, one wave
{
    int l = threadIdx.x;
    int orig = (l < 49) ? bsums[l] : 0;
    int v = orig;
    #pragma unroll
    for (int d = 1; d < 64; d <<= 1) { int u = __shfl_up(v, d); if (l >= d) v += u; }
    if (l < 49) bsums[l] = v - orig;   // exclusive
}

__global__ __launch_bounds__(256) void scan_final(
    const int* __restrict__ deg, const int* __restrict__ bsums,
    int* __restrict__ offs, int* __restrict__ cursor)
{
    __shared__ int sd[256];
    int t = threadIdx.x, base = blockIdx.x * 1024;
    int v[4]; int sum = 0;
    #pragma unroll
    for (int i = 0; i < 4; ++i) { int idx = base + t * 4 + i; v[i] = (idx < NNODES) ? deg[idx] : 0; sum += v[i]; }
    sd[t] = sum; __syncthreads();
    int val = sum;
    for (int st = 1; st < 256; st <<= 1) {
        int add = (t >= st) ? sd[t - st] : 0;
        __syncthreads();
        val += add; sd[t] = val;
        __syncthreads();
    }
    int run = bsums[blockIdx.x] + (val - sum);
    #pragma unroll
    for (int i = 0; i < 4; ++i) {
        int idx = base + t * 4 + i;
        if (idx < NNODES) { offs[idx] = run; cursor[idx] = run; }
        run += v[i];
    }
    if (blockIdx.x == 0 && t == 0) offs[NNODES] = NEDGES;
}

// scatter writes {src, e} packed — agg needs no eidx->src indirection
__global__ void scatter_k(const int* __restrict__ dstv, const int* __restrict__ src,
                          int* __restrict__ cursor, int2* __restrict__ perm)
{
    int e = blockIdx.x * blockDim.x + threadIdx.x;
    if (e < NEDGES) {
        int pos = atomicAdd(&cursor[dstv[e]], 1);
        perm[pos] = make_int2(src[e], e);
    }
}

// ---------------------------------------------------------------------------
// Aggregation (fused softmax): one wave per dst node; lane l owns cols
// [8l, 8l+8), head = l>>3. Max-free softmax (logits bounded ~±45 << 88).
// Unroll x4: 4 independent 1KB hmat rows in flight per wave.
// ---------------------------------------------------------------------------
__global__ __launch_bounds__(256) void agg_k(
    const int* __restrict__ offs, const int2* __restrict__ perm,
    const float* __restrict__ esrc, const float* __restrict__ edst,
    const float* __restrict__ dist, const __bf16* __restrict__ hmat,
    float* __restrict__ out)
{
    int node = blockIdx.x * 4 + (threadIdx.x >> 6);
    int lane = threadIdx.x & 63;
    if (node >= NNODES) return;
    const int head = lane >> 3;
    const float edv = edst[(size_t)node * NHEADS + head];
    int beg = offs[node], end = offs[node + 1];
    float denom = 0.f;
    float acc[8] = {};

    int pos = beg;
    for (; pos + 4 <= end; pos += 4) {
        int2 a0 = perm[pos], a1 = perm[pos + 1], a2 = perm[pos + 2], a3 = perm[pos + 3];
        // issue all gathers up front (independent)
        float es0 = esrc[(size_t)a0.x * NHEADS + head];
        float es1 = esrc[(size_t)a1.x * NHEADS + head];
        float es2 = esrc[(size_t)a2.x * NHEADS + head];
        float es3 = esrc[(size_t)a3.x * NHEADS + head];
        float di0 = dist[(size_t)a0.y * NHEADS + head];
        float di1 = dist[(size_t)a1.y * NHEADS + head];
        float di2 = dist[(size_t)a2.y * NHEADS + head];
        float di3 = dist[(size_t)a3.y * NHEADS + head];
        bf16x8 h0 = *(const bf16x8*)(hmat + (size_t)a0.x * OUTD + lane * 8);
        bf16x8 h1 = *(const bf16x8*)(hmat + (size_t)a1.x * OUTD + lane * 8);
        bf16x8 h2 = *(const bf16x8*)(hmat + (size_t)a2.x * OUTD + lane * 8);
        bf16x8 h3 = *(const bf16x8*)(hmat + (size_t)a3.x * OUTD + lane * 8);
        float ex0 = __expf(lrelu(es0 + edv));
        float ex1 = __expf(lrelu(es1 + edv));
        float ex2 = __expf(lrelu(es2 + edv));
        float ex3 = __expf(lrelu(es3 + edv));
        denom += (ex0 + ex1) + (ex2 + ex3);
        float w0 = ex0 * di0, w1 = ex1 * di1, w2 = ex2 * di2, w3 = ex3 * di3;
        #pragma unroll
        for (int j = 0; j < 8; ++j)
            acc[j] += (w0 * (float)h0[j] + w1 * (float)h1[j])
                    + (w2 * (float)h2[j] + w3 * (float)h3[j]);
    }
    for (; pos < end; ++pos) {
        int2 a0 = perm[pos];
        float es0 = esrc[(size_t)a0.x * NHEADS + head];
        float di0 = dist[(size_t)a0.y * NHEADS + head];
        bf16x8 h0 = *(const bf16x8*)(hmat + (size_t)a0.x * OUTD + lane * 8);
        float ex0 = __expf(lrelu(es0 + edv));
        denom += ex0;
        float w0 = ex0 * di0;
        #pragma unroll
        for (int j = 0; j < 8; ++j) acc[j] += w0 * (float)h0[j];
    }

    float sinv = denom > 0.f ? 1.f / denom : 0.f;
    f32x4 o0 = {acc[0] * sinv, acc[1] * sinv, acc[2] * sinv, acc[3] * sinv};
    f32x4 o1 = {acc[4] * sinv, acc[5] * sinv, acc[6] * sinv, acc[7] * sinv};
    *(f32x4*)(out + (size_t)node * OUTD + lane * 8)     = o0;
    *(f32x4*)(out + (size_t)node * OUTD + lane * 8 + 4) = o1;
}

// ---------------------------------------------------------------------------
extern "C" void kernel_launch(void* const* d_in, const int* in_sizes, int n_in,
                              void* d_out, int out_size, void* d_ws, size_t ws_size,
                              hipStream_t stream)
{
    const float* feat = (const float*)d_in[0];
    const float* dist = (const float*)d_in[1];
    const int*   src  = (const int*)d_in[2];
    const int*   dstv = (const int*)d_in[3];
    const float* W    = (const float*)d_in[4];
    const float* bias = (const float*)d_in[5];
    const float* w_s  = (const float*)d_in[6];
    const float* w_d  = (const float*)d_in[7];
    float* out = (float*)d_out;

    char* wsb = (char*)d_ws;
    size_t off = 0;
    auto alloc = [&](size_t bytes) -> char* {
        char* r = wsb + off;
        off = (off + bytes + 255) & ~(size_t)255;
        return r;
    };
    __bf16* hmat  = (__bf16*)alloc((size_t)NNODES * OUTD * 2);   // 51.2 MB
    float*  esrc  = (float*)alloc((size_t)NNODES * NHEADS * 4);  // 1.6 MB
    float*  edst  = (float*)alloc((size_t)NNODES * NHEADS * 4);
    int*    deg   = (int*)alloc((size_t)NNODES * 4);
    int*    offs  = (int*)alloc((size_t)(NNODES + 1) * 4);
    int*    cursor= (int*)alloc((size_t)NNODES * 4);
    int2*   perm  = (int2*)alloc((size_t)NEDGES * 8);            // 6.4 MB
    int*    bsums = (int*)alloc(64 * 4);

    hipMemsetAsync(deg, 0, (size_t)NNODES * 4, stream);

    gemm_h<<<dim3((NNODES + BM - 1) / BM, OUTD / BN), 256, 0, stream>>>(
        feat, W, bias, w_s, w_d, hmat, esrc, edst, dstv, deg);

    scan_bsums<<<49, 256, 0, stream>>>(deg, bsums);
    scan_partials<<<1, 64, 0, stream>>>(bsums);
    scan_final<<<49, 256, 0, stream>>>(deg, bsums, offs, cursor);
    scatter_k<<<(NEDGES + 255) / 256, 256, 0, stream>>>(dstv, src, cursor, perm);

    agg_k<<<(NNODES + 3) / 4, 256, 0, stream>>>(offs, perm, esrc, edst, dist, hmat, out);
}

// Round 7
// 484.531 us; speedup vs baseline: 1.8695x; 1.0822x over previous
//
#include <hip/hip_runtime.h>

#define NNODES 50000
#define NEDGES 800000
#define INDIM  512
#define OUTD   512   // NUM_HEADS * OUT_DIM
#define NHEADS 8

typedef float  f32x4  __attribute__((ext_vector_type(4)));
typedef __bf16 bf16x8 __attribute__((ext_vector_type(8)));

__device__ __forceinline__ float lrelu(float x) { return x > 0.f ? x : 0.2f * x; }

// ---------------------------------------------------------------------------
// cvt: f32 -> bf16, vectorized 8/thread (G13)
// ---------------------------------------------------------------------------
__global__ __launch_bounds__(256) void cvt_k(const float* __restrict__ f,
                                             __bf16* __restrict__ o, int n8)
{
    int i = blockIdx.x * 256 + threadIdx.x;
    int stride = gridDim.x * 256;
    for (; i < n8; i += stride) {
        f32x4 a = *(const f32x4*)(f + (size_t)i * 8);
        f32x4 b = *(const f32x4*)(f + (size_t)i * 8 + 4);
        bf16x8 v;
        v[0]=(__bf16)a[0]; v[1]=(__bf16)a[1]; v[2]=(__bf16)a[2]; v[3]=(__bf16)a[3];
        v[4]=(__bf16)b[0]; v[5]=(__bf16)b[1]; v[6]=(__bf16)b[2]; v[7]=(__bf16)b[3];
        *(bf16x8*)(o + (size_t)i * 8) = v;
    }
}

// ---------------------------------------------------------------------------
// GEMM: h = leaky_relu(featb @ Wb^T + b), bf16 MFMA, f32 acc.
// m97-style: global_load_lds width=16 staging, BK=64, XOR-swizzled LDS
// (pre-swizzled global source + swizzled ds_read; LDS dest stays linear).
// Tile 128x128, 4 waves 2x2, each wave 64x64 = 4x4 16x16x32 frags x 2 K-steps.
// Grid (4 cols, 391 rows): col-tiles of same rows temporally adjacent.
// Fused: edge histogram + per-head logits epilogue.
// ---------------------------------------------------------------------------
constexpr int BM = 128, BN = 128;

__global__ __launch_bounds__(256) void gemm_h(
    const __bf16* __restrict__ featb, const __bf16* __restrict__ Wb,
    const float* __restrict__ bias, const float* __restrict__ w_s,
    const float* __restrict__ w_d, __bf16* __restrict__ hout,
    float* __restrict__ esrc, float* __restrict__ edst,
    const int* __restrict__ dstv, int* __restrict__ deg)
{
    __shared__ __bf16 As[BM][64];   // 16 KB, row = 128 B
    __shared__ __bf16 Bs[BN][64];   // 16 KB
    const int col0 = blockIdx.x * BN;     // 4 col tiles
    const int row0 = blockIdx.y * BM;     // 391 row tiles
    const int tid  = threadIdx.x;

    // ---- fused edge histogram: this block's 512-edge slice ----
    {
        int bid = blockIdx.y * gridDim.x + blockIdx.x;   // 0..1563
        int lo = bid * 512, hi = lo + 512;
        if (hi > NEDGES) hi = NEDGES;
        for (int e = lo + tid; e < hi; e += 256)
            atomicAdd(&deg[dstv[e]], 1);
    }

    const int lane = tid & 63;
    const int w    = tid >> 6;
    const int wr   = w >> 1, wc = w & 1;
    const int lr   = lane & 15, kg = lane >> 4;

    // staging: physical LDS chunk p = tid + 256*i; r = p>>3, ps = p&7.
    // source logical 16B-chunk sub = ps ^ (r&7)  (involution with read side)
    int srcA[4], srcB[4];   // element offsets, hoisted
    #pragma unroll
    for (int i = 0; i < 4; ++i) {
        int p = tid + 256 * i;
        int r = p >> 3, ps = p & 7, sub = ps ^ (r & 7);
        int gra = row0 + r; if (gra > NNODES - 1) gra = NNODES - 1;
        srcA[i] = gra * INDIM + sub * 8;
        srcB[i] = (col0 + r) * INDIM + sub * 8;
    }

    f32x4 acc[4][4] = {};

    for (int k0 = 0; k0 < INDIM; k0 += 64) {
        #pragma unroll
        for (int i = 0; i < 4; ++i) {
            int p = tid + 256 * i;
            __builtin_amdgcn_global_load_lds(
                (const __attribute__((address_space(1))) void*)(featb + srcA[i] + k0),
                (__attribute__((address_space(3))) void*)((char*)&As[0][0] + p * 16),
                16, 0, 0);
            __builtin_amdgcn_global_load_lds(
                (const __attribute__((address_space(1))) void*)(Wb + srcB[i] + k0),
                (__attribute__((address_space(3))) void*)((char*)&Bs[0][0] + p * 16),
                16, 0, 0);
        }
        __syncthreads();   // drains vmcnt: LDS tiles complete
        #pragma unroll
        for (int ks = 0; ks < 2; ++ks) {
            bf16x8 af[4], bf[4];
            const int pc = ((ks * 4 + kg) ^ (lr & 7)) * 16;   // swizzled chunk
            #pragma unroll
            for (int mi = 0; mi < 4; ++mi)
                af[mi] = *(const bf16x8*)((const char*)&As[0][0] + (wr*64 + mi*16 + lr) * 128 + pc);
            #pragma unroll
            for (int ni = 0; ni < 4; ++ni)
                bf[ni] = *(const bf16x8*)((const char*)&Bs[0][0] + (wc*64 + ni*16 + lr) * 128 + pc);
            #pragma unroll
            for (int mi = 0; mi < 4; ++mi)
                #pragma unroll
                for (int ni = 0; ni < 4; ++ni)
                    acc[mi][ni] = __builtin_amdgcn_mfma_f32_16x16x32_bf16(af[mi], bf[ni], acc[mi][ni], 0, 0, 0);
        }
        __syncthreads();
    }

    // epilogue: bias + leakyrelu, store bf16 h, fused per-head logits
    float cb[4], wsv[4], wdv[4];
    #pragma unroll
    for (int ni = 0; ni < 4; ++ni) {
        int c = col0 + wc * 64 + ni * 16 + lr;
        cb[ni]  = bias[c];
        wsv[ni] = w_s[c];
        wdv[ni] = w_d[c];
    }
    const int head = (col0 + wc * 64) >> 6;   // wave spans exactly one head
    #pragma unroll
    for (int mi = 0; mi < 4; ++mi) {
        #pragma unroll
        for (int reg = 0; reg < 4; ++reg) {
            int r = row0 + wr * 64 + mi * 16 + kg * 4 + reg;   // C/D: row=(l>>4)*4+reg
            bool valid = r < NNODES;
            float vs = 0.f, vd = 0.f;
            #pragma unroll
            for (int ni = 0; ni < 4; ++ni) {
                int c = col0 + wc * 64 + ni * 16 + lr;          // C/D: col=l&15
                float v = acc[mi][ni][reg] + cb[ni];
                v = lrelu(v);
                if (valid) hout[(size_t)r * OUTD + c] = (__bf16)v;
                vs += v * wsv[ni];
                vd += v * wdv[ni];
            }
            #pragma unroll
            for (int m = 1; m < 16; m <<= 1) { vs += __shfl_xor(vs, m); vd += __shfl_xor(vd, m); }
            if (valid && lr == 0) {
                esrc[r * NHEADS + head] = vs;
                edst[r * NHEADS + head] = vd;
            }
        }
    }
}

// ---------------------------------------------------------------------------
// CSR build: (histogram fused into gemm_h) -> 3-phase scan -> scatter
// ---------------------------------------------------------------------------
__global__ __launch_bounds__(256) void scan_bsums(const int* __restrict__ deg, int* __restrict__ bsums)
{
    __shared__ int sd[256];
    int t = threadIdx.x, base = blockIdx.x * 1024, sum = 0;
    #pragma unroll
    for (int i = 0; i < 4; ++i) { int idx = base + t * 4 + i; if (idx < NNODES) sum += deg[idx]; }
    sd[t] = sum; __syncthreads();
    for (int st = 128; st > 0; st >>= 1) { if (t < st) sd[t] += sd[t + st]; __syncthreads(); }
    if (t == 0) bsums[blockIdx.x] = sd[0];
}

__global__ void scan_partials(int* __restrict__ bsums)   // 49 partials, one wave
{
    int l = threadIdx.x;
    int orig = (l < 49) ? bsums[l] : 0;
    int v = orig;
    #pragma unroll
    for (int d = 1; d < 64; d <<= 1) { int u = __shfl_up(v, d); if (l >= d) v += u; }
    if (l < 49) bsums[l] = v - orig;   // exclusive
}

__global__ __launch_bounds__(256) void scan_final(
    const int* __restrict__ deg, const int* __restrict__ bsums,
    int* __restrict__ offs, int* __restrict__ cursor)
{
    __shared__ int sd[256];
    int t = threadIdx.x, base = blockIdx.x * 1024;
    int v[4]; int sum = 0;
    #pragma unroll
    for (int i = 0; i < 4; ++i) { int idx = base + t * 4 + i; v[i] = (idx < NNODES) ? deg[idx] : 0; sum += v[i]; }
    sd[t] = sum; __syncthreads();
    int val = sum;
    for (int st = 1; st < 256; st <<= 1) {
        int add = (t >= st) ? sd[t - st] : 0;
        __syncthreads();
        val += add; sd[t] = val;
        __syncthreads();
    }
    int run = bsums[blockIdx.x] + (val - sum);
    #pragma unroll
    for (int i = 0; i < 4; ++i) {
        int idx = base + t * 4 + i;
        if (idx < NNODES) { offs[idx] = run; cursor[idx] = run; }
        run += v[i];
    }
    if (blockIdx.x == 0 && t == 0) offs[NNODES] = NEDGES;
}

// scatter writes {src, e} packed — agg needs no eidx->src indirection
__global__ void scatter_k(const int* __restrict__ dstv, const int* __restrict__ src,
                          int* __restrict__ cursor, int2* __restrict__ perm)
{
    int e = blockIdx.x * blockDim.x + threadIdx.x;
    if (e < NEDGES) {
        int pos = atomicAdd(&cursor[dstv[e]], 1);
        perm[pos] = make_int2(src[e], e);
    }
}

// ---------------------------------------------------------------------------
// Aggregation (fused softmax): one wave per dst node; lane l owns cols
// [8l, 8l+8), head = l>>3. Max-free softmax (logits bounded ~±45 << 88).
// Unroll x4: 4 independent 1KB hmat rows in flight per wave.
// ---------------------------------------------------------------------------
__global__ __launch_bounds__(256) void agg_k(
    const int* __restrict__ offs, const int2* __restrict__ perm,
    const float* __restrict__ esrc, const float* __restrict__ edst,
    const float* __restrict__ dist, const __bf16* __restrict__ hmat,
    float* __restrict__ out)
{
    int node = blockIdx.x * 4 + (threadIdx.x >> 6);
    int lane = threadIdx.x & 63;
    if (node >= NNODES) return;
    const int head = lane >> 3;
    const float edv = edst[(size_t)node * NHEADS + head];
    int beg = offs[node], end = offs[node + 1];
    float denom = 0.f;
    float acc[8] = {};

    int pos = beg;
    for (; pos + 4 <= end; pos += 4) {
        int2 a0 = perm[pos], a1 = perm[pos + 1], a2 = perm[pos + 2], a3 = perm[pos + 3];
        float es0 = esrc[(size_t)a0.x * NHEADS + head];
        float es1 = esrc[(size_t)a1.x * NHEADS + head];
        float es2 = esrc[(size_t)a2.x * NHEADS + head];
        float es3 = esrc[(size_t)a3.x * NHEADS + head];
        float di0 = dist[(size_t)a0.y * NHEADS + head];
        float di1 = dist[(size_t)a1.y * NHEADS + head];
        float di2 = dist[(size_t)a2.y * NHEADS + head];
        float di3 = dist[(size_t)a3.y * NHEADS + head];
        bf16x8 h0 = *(const bf16x8*)(hmat + (size_t)a0.x * OUTD + lane * 8);
        bf16x8 h1 = *(const bf16x8*)(hmat + (size_t)a1.x * OUTD + lane * 8);
        bf16x8 h2 = *(const bf16x8*)(hmat + (size_t)a2.x * OUTD + lane * 8);
        bf16x8 h3 = *(const bf16x8*)(hmat + (size_t)a3.x * OUTD + lane * 8);
        float ex0 = __expf(lrelu(es0 + edv));
        float ex1 = __expf(lrelu(es1 + edv));
        float ex2 = __expf(lrelu(es2 + edv));
        float ex3 = __expf(lrelu(es3 + edv));
        denom += (ex0 + ex1) + (ex2 + ex3);
        float w0 = ex0 * di0, w1 = ex1 * di1, w2 = ex2 * di2, w3 = ex3 * di3;
        #pragma unroll
        for (int j = 0; j < 8; ++j)
            acc[j] += (w0 * (float)h0[j] + w1 * (float)h1[j])
                    + (w2 * (float)h2[j] + w3 * (float)h3[j]);
    }
    for (; pos < end; ++pos) {
        int2 a0 = perm[pos];
        float es0 = esrc[(size_t)a0.x * NHEADS + head];
        float di0 = dist[(size_t)a0.y * NHEADS + head];
        bf16x8 h0 = *(const bf16x8*)(hmat + (size_t)a0.x * OUTD + lane * 8);
        float ex0 = __expf(lrelu(es0 + edv));
        denom += ex0;
        float w0 = ex0 * di0;
        #pragma unroll
        for (int j = 0; j < 8; ++j) acc[j] += w0 * (float)h0[j];
    }

    float sinv = denom > 0.f ? 1.f / denom : 0.f;
    f32x4 o0 = {acc[0] * sinv, acc[1] * sinv, acc[2] * sinv, acc[3] * sinv};
    f32x4 o1 = {acc[4] * sinv, acc[5] * sinv, acc[6] * sinv, acc[7] * sinv};
    *(f32x4*)(out + (size_t)node * OUTD + lane * 8)     = o0;
    *(f32x4*)(out + (size_t)node * OUTD + lane * 8 + 4) = o1;
}

// ---------------------------------------------------------------------------
extern "C" void kernel_launch(void* const* d_in, const int* in_sizes, int n_in,
                              void* d_out, int out_size, void* d_ws, size_t ws_size,
                              hipStream_t stream)
{
    const float* feat = (const float*)d_in[0];
    const float* dist = (const float*)d_in[1];
    const int*   src  = (const int*)d_in[2];
    const int*   dstv = (const int*)d_in[3];
    const float* W    = (const float*)d_in[4];
    const float* bias = (const float*)d_in[5];
    const float* w_s  = (const float*)d_in[6];
    const float* w_d  = (const float*)d_in[7];
    float* out = (float*)d_out;

    char* wsb = (char*)d_ws;
    size_t off = 0;
    auto alloc = [&](size_t bytes) -> char* {
        char* r = wsb + off;
        off = (off + bytes + 255) & ~(size_t)255;
        return r;
    };
    __bf16* hmat  = (__bf16*)alloc((size_t)NNODES * OUTD * 2);   // 51.2 MB
    __bf16* featb = (__bf16*)alloc((size_t)NNODES * INDIM * 2);  // 51.2 MB
    __bf16* Wb    = (__bf16*)alloc((size_t)OUTD * INDIM * 2);    // 0.5 MB
    float*  esrc  = (float*)alloc((size_t)NNODES * NHEADS * 4);  // 1.6 MB
    float*  edst  = (float*)alloc((size_t)NNODES * NHEADS * 4);
    int*    deg   = (int*)alloc((size_t)NNODES * 4);
    int*    offs  = (int*)alloc((size_t)(NNODES + 1) * 4);
    int*    cursor= (int*)alloc((size_t)NNODES * 4);
    int2*   perm  = (int2*)alloc((size_t)NEDGES * 8);            // 6.4 MB
    int*    bsums = (int*)alloc(64 * 4);

    hipMemsetAsync(deg, 0, (size_t)NNODES * 4, stream);

    cvt_k<<<2048, 256, 0, stream>>>(feat, featb, NNODES * INDIM / 8);
    cvt_k<<<128, 256, 0, stream>>>(W, Wb, OUTD * INDIM / 8);

    gemm_h<<<dim3(OUTD / BN, (NNODES + BM - 1) / BM), 256, 0, stream>>>(
        featb, Wb, bias, w_s, w_d, hmat, esrc, edst, dstv, deg);

    scan_bsums<<<49, 256, 0, stream>>>(deg, bsums);
    scan_partials<<<1, 64, 0, stream>>>(bsums);
    scan_final<<<49, 256, 0, stream>>>(deg, bsums, offs, cursor);
    scatter_k<<<(NEDGES + 255) / 256, 256, 0, stream>>>(dstv, src, cursor, perm);

    agg_k<<<(NNODES + 3) / 4, 256, 0, stream>>>(offs, perm, esrc, edst, dist, hmat, out);
}